// Round 1
// baseline (1458.587 us; speedup 1.0000x reference)
//
#include <hip/hip_runtime.h>

// UAG-RNN 4-neighbor: two directional scans (vertical then horizontal).
// Reference semantics:
//   V: row0 = x[:, :, 0, :] (raw);  row_h = relu(W1 x_h + b1 + W2 row_{h-1} + b2)
//   H: col0 = relu(hs col0);        col_j = relu(W4 c_j + b4 + W5 col_{j-1} + b5)
//
// Key layout trick: the vertical pass writes its output TRANSPOSED as
// hsT[b][c][w][h]. Then the horizontal pass has byte-identical addressing:
//   in_idx (b,c,step,pos) = ((b*64+c)*384 + step)*384 + pos
//   out_idx(b,c,pos,step) = ((b*64+c)*384 + pos )*384 + step
// One kernel, mode flag only changes the step-0 init (relu or not).

#define C64 64
#define S   384     // steps per scan == H == W
#define PP  6       // positions per workgroup (1536 positions / 256 WGs)
#define TPB (C64 * PP)   // 384 threads = 6 waves
#define LDP 68      // padded LDS row (16B-aligned rows, conflict-free writes)

__global__ __launch_bounds__(TPB, 2)
void scan_kernel(const float* __restrict__ in, float* __restrict__ out,
                 const float* __restrict__ Wa, const float* __restrict__ ba,
                 const float* __restrict__ Wb, const float* __restrict__ bb,
                 int mode)
{
    __shared__ float xs[2][PP][LDP];   // staged input rows (double-buffered)
    __shared__ float vs[2][PP][LDP];   // recurrent state rows (double-buffered)

    const int t  = threadIdx.x;
    const int o  = t & 63;        // output channel (compute mapping)
    const int pl = t >> 6;        // local position (compute mapping)
    const int lc = t / PP;        // channel (load mapping)
    const int lp = t - lc * PP;   // local position (load mapping)

    const int wg = blockIdx.x;    // 0..255
    const int P0 = wg * PP;       // global position base (p = b*S + pos)
    const int b  = P0 / S;
    const int w0 = P0 - b * S;    // PP consecutive positions, single b (6|384)

    // ---- weights into registers: row o of Wa and Wb (64 + 64 VGPRs) ----
    float wa[C64], wb[C64];
    {
        const float4* A4 = (const float4*)(Wa + o * C64);
        const float4* B4 = (const float4*)(Wb + o * C64);
#pragma unroll
        for (int i = 0; i < 16; ++i) {
            float4 qa = A4[i];
            float4 qb = B4[i];
            wa[4*i+0] = qa.x; wa[4*i+1] = qa.y; wa[4*i+2] = qa.z; wa[4*i+3] = qa.w;
            wb[4*i+0] = qb.x; wb[4*i+1] = qb.y; wb[4*i+2] = qb.z; wb[4*i+3] = qb.w;
        }
    }
    const float bias = ba[o] + bb[o];

    // ---- addressing ----
    const int inb   = ((b*C64 + lc) * S) * S + (w0 + lp);        // (lc,lp): + step*S
    const int outb  = ((b*C64 + o)  * S + (w0 + pl)) * S;        // (o,pl):  + step
    const int outb0 = ((b*C64 + lc) * S + (w0 + lp)) * S;        // (lc,lp) step-0 store

    // ---- step 0 init ----
    float v0 = in[inb];                 // step 0 element for (lc, lp)
    if (mode) v0 = fmaxf(v0, 0.0f);
    out[outb0] = v0;                    // step-0 output (raw for V, relu'd for H)
    vs[1][lp][lc] = v0;                 // state for iteration h=1 (parity 1)
    xs[1][lp][lc] = in[inb + 1 * S];    // input row for h=1
    float xreg = in[inb + 2 * S];       // prefetch input row for h=2
    __syncthreads();

    // ---- sequential scan ----
    for (int h = 1; h < S; ++h) {
        const int par = h & 1;
        const float4* xq4 = (const float4*)&xs[par][pl][0];
        const float4* vq4 = (const float4*)&vs[par][pl][0];

        float a0 = bias, a1 = 0.0f, a2 = 0.0f, a3 = 0.0f;
#pragma unroll
        for (int i = 0; i < 16; ++i) {
            float4 xq = xq4[i];   // broadcast reads: whole wave shares pl
            float4 vq = vq4[i];
            a0 = fmaf(wa[4*i+0], xq.x, a0);
            a1 = fmaf(wa[4*i+1], xq.y, a1);
            a2 = fmaf(wa[4*i+2], xq.z, a2);
            a3 = fmaf(wa[4*i+3], xq.w, a3);
            a0 = fmaf(wb[4*i+0], vq.x, a0);
            a1 = fmaf(wb[4*i+1], vq.y, a1);
            a2 = fmaf(wb[4*i+2], vq.z, a2);
            a3 = fmaf(wb[4*i+3], vq.w, a3);
        }
        float vnew = fmaxf((a0 + a1) + (a2 + a3), 0.0f);

        out[outb + h] = vnew;   // L2 write-combines along h

        if (h < S - 1) {
            vs[par ^ 1][pl][o]  = vnew;   // state for next step
            xs[par ^ 1][lp][lc] = xreg;   // input row for next step
            int hn = h + 2; if (hn > S - 1) hn = S - 1;   // harmless re-load at tail
            xreg = in[inb + hn * S];
            __syncthreads();
        }
    }
}

extern "C" void kernel_launch(void* const* d_in, const int* in_sizes, int n_in,
                              void* d_out, int out_size, void* d_ws, size_t ws_size,
                              hipStream_t stream) {
    const float* x  = (const float*)d_in[0];
    const float* W1 = (const float*)d_in[1];
    const float* b1 = (const float*)d_in[2];
    const float* W2 = (const float*)d_in[3];
    const float* b2 = (const float*)d_in[4];
    const float* W4 = (const float*)d_in[5];
    const float* b4 = (const float*)d_in[6];
    const float* W5 = (const float*)d_in[7];
    const float* b5 = (const float*)d_in[8];
    float* out = (float*)d_out;
    float* hsT = (float*)d_ws;   // B*C*W*H floats = 150,994,944 bytes of scratch

    dim3 grid(256), block(TPB);
    // Vertical pass: reads x[b][c][h][w], writes hsT[b][c][w][h]
    scan_kernel<<<grid, block, 0, stream>>>(x,   hsT, W1, b1, W2, b2, 0);
    // Horizontal pass: reads hsT[b][c][j][h], writes out[b][c][h][j]
    scan_kernel<<<grid, block, 0, stream>>>(hsT, out, W4, b4, W5, b5, 1);
}

// Round 2
// 1249.939 us; speedup vs baseline: 1.1669x; 1.1669x over previous
//
#include <hip/hip_runtime.h>

// UAG-RNN 4-neighbor, two directional scans.
// Round-2 structure: ONE WAVE PER POSITION (WG = 64 threads), lane = channel.
//  - cross-channel exchange via 256B LDS rows inside the wave: no s_barrier,
//    no vmcnt(0) drain per step (the round-1 killer).
//  - __launch_bounds__(64,2) so the 128 weight floats stay in VGPRs
//    (round 1: VGPR_Count=84 => weights were rematerialized from L1 every step).
//  - input prefetch 3 steps deep (scattered scalar loads, latency hidden).
//  - output batched 4 steps -> global_store_dwordx4 (contiguous along step dim).
//
// Layout trick (unchanged): vertical pass writes hsT[b][c][w][h], so both
// passes use identical addressing:
//   in  (b,c,step,pos): ((b*64+c)*384 + step)*384 + pos
//   out (b,c,pos,step): ((b*64+c)*384 + pos )*384 + step

#define C64 64
#define S   384

typedef float v2f __attribute__((ext_vector_type(2)));

static __device__ __forceinline__ v2f mk2(float a, float b) {
    v2f r; r.x = a; r.y = b; return r;
}

__global__ __launch_bounds__(64, 2)
void scan_kernel(const float* __restrict__ in, float* __restrict__ out,
                 const float* __restrict__ Wa, const float* __restrict__ ba,
                 const float* __restrict__ Wb, const float* __restrict__ bb,
                 int mode)
{
    __shared__ float xs[2][C64];   // staged input row (double-buffered)
    __shared__ float vs[2][C64];   // recurrent state row (double-buffered)

    const int o   = threadIdx.x;        // lane = channel (load AND compute)
    const int g   = blockIdx.x;         // 0..1535 : (b, pos)
    const int b   = g / S;
    const int pos = g - b * S;

    // ---- weights row o into registers as float2 pairs (128 VGPRs) ----
    v2f wa2[32], wb2[32];
    {
        const float4* A4 = (const float4*)(Wa + o * C64);
        const float4* B4 = (const float4*)(Wb + o * C64);
#pragma unroll
        for (int i = 0; i < 16; ++i) {
            float4 qa = A4[i], qb = B4[i];
            wa2[2*i+0] = mk2(qa.x, qa.y);
            wa2[2*i+1] = mk2(qa.z, qa.w);
            wb2[2*i+0] = mk2(qb.x, qb.y);
            wb2[2*i+1] = mk2(qb.z, qb.w);
        }
    }
    const float bias = ba[o] + bb[o];

    const int inb  = ((b*C64 + o) * S) * S + pos;   // + step*S
    const int outb = ((b*C64 + o) * S + pos) * S;   // + step

    // ---- step 0 init + 3-deep input prefetch ----
    float v0 = in[inb];
    if (mode) v0 = fmaxf(v0, 0.0f);
    vs[1][o] = v0;
    xs[1][o] = in[inb + 1*S];
    float xr  = in[inb + 2*S];
    float xr2 = in[inb + 3*S];
    __builtin_amdgcn_wave_barrier();

    float4 obuf;
    obuf.x = v0;

    // One scan step. H = step index, PAR = H&1 (compile-time per slot),
    // MEM = obuf member for this step. Refill at H==383 is harmless
    // (clamped load, dead LDS write).
#define STEP(H, PAR, MEM)                                                     \
    {                                                                         \
        const float4* xq4 = (const float4*)&xs[PAR][0];                       \
        const float4* vq4 = (const float4*)&vs[PAR][0];                       \
        v2f a0 = mk2(bias, 0.0f), a1 = mk2(0.f,0.f);                          \
        v2f a2 = mk2(0.f,0.f),    a3 = mk2(0.f,0.f);                          \
        _Pragma("unroll")                                                     \
        for (int i = 0; i < 16; ++i) {                                        \
            float4 xq = xq4[i];   /* wave-broadcast LDS reads */              \
            float4 vq = vq4[i];                                               \
            a0 = __builtin_elementwise_fma(wa2[2*i+0], mk2(xq.x,xq.y), a0);   \
            a1 = __builtin_elementwise_fma(wa2[2*i+1], mk2(xq.z,xq.w), a1);   \
            a2 = __builtin_elementwise_fma(wb2[2*i+0], mk2(vq.x,vq.y), a2);   \
            a3 = __builtin_elementwise_fma(wb2[2*i+1], mk2(vq.z,vq.w), a3);   \
        }                                                                     \
        v2f sv = (a0 + a1) + (a2 + a3);                                       \
        float vnew = fmaxf(sv.x + sv.y, 0.0f);                                \
        obuf.MEM = vnew;                                                      \
        vs[PAR ^ 1][o] = vnew;        /* state for step H+1 */                \
        xs[PAR ^ 1][o] = xr;          /* input row for step H+1 */            \
        xr = xr2;                                                             \
        int hn = (H) + 3; hn = (hn > S-1) ? (S-1) : hn;                       \
        xr2 = in[inb + hn * S];                                               \
        __builtin_amdgcn_wave_barrier();                                      \
    }

    // ---- peel: steps 1..3, store batch h=0..3 ----
    STEP(1, 1, y)
    STEP(2, 0, z)
    STEP(3, 1, w)
    *(float4*)(out + outb) = obuf;

    // ---- main: k = 1..95, steps 4k..4k+3, store batch per k ----
    for (int k = 1; k < 96; ++k) {
        const int h0 = 4 * k;
        STEP(h0 + 0, 0, x)
        STEP(h0 + 1, 1, y)
        STEP(h0 + 2, 0, z)
        STEP(h0 + 3, 1, w)
        *(float4*)(out + outb + h0) = obuf;
    }
#undef STEP
}

extern "C" void kernel_launch(void* const* d_in, const int* in_sizes, int n_in,
                              void* d_out, int out_size, void* d_ws, size_t ws_size,
                              hipStream_t stream) {
    const float* x  = (const float*)d_in[0];
    const float* W1 = (const float*)d_in[1];
    const float* b1 = (const float*)d_in[2];
    const float* W2 = (const float*)d_in[3];
    const float* b2 = (const float*)d_in[4];
    const float* W4 = (const float*)d_in[5];
    const float* b4 = (const float*)d_in[6];
    const float* W5 = (const float*)d_in[7];
    const float* b5 = (const float*)d_in[8];
    float* out = (float*)d_out;
    float* hsT = (float*)d_ws;   // B*C*W*H floats of scratch

    dim3 grid(4 * S), block(C64);   // 1536 waves, one per (b, pos)
    // Vertical: reads x[b][c][h][w], writes hsT[b][c][w][h]
    scan_kernel<<<grid, block, 0, stream>>>(x,   hsT, W1, b1, W2, b2, 0);
    // Horizontal: reads hsT[b][c][j][h], writes out[b][c][h][j]
    scan_kernel<<<grid, block, 0, stream>>>(hsT, out, W4, b4, W5, b5, 1);
}

// Round 3
// 929.905 us; speedup vs baseline: 1.5685x; 1.3442x over previous
//
#include <hip/hip_runtime.h>

// UAG-RNN 4-neighbor, two directional scans. One wave per position, lane=channel.
// Round-3 changes:
//  - weights pinned in VGPRs via empty `asm volatile("" : "+v")` — a volatile
//    asm result cannot be rematerialized, so the allocator must keep all 128
//    weight floats resident (rounds 1-2: VGPR_Count=84 proved the compiler
//    re-loaded weights from memory every loop iteration => load-wait bound).
//  - output batched 16 steps -> 4x global_store_dwordx4 covering a full 64B
//    line per lane (round 2: WRITE_SIZE 375MB vs 151MB ideal = partial lines).
//
// Layout trick (unchanged): vertical pass writes hsT[b][c][w][h], so both
// passes use identical addressing:
//   in  (b,c,step,pos): ((b*64+c)*384 + step)*384 + pos
//   out (b,c,pos,step): ((b*64+c)*384 + pos )*384 + step

#define C64 64
#define S   384

typedef float v2f __attribute__((ext_vector_type(2)));

static __device__ __forceinline__ v2f mk2(float a, float b) {
    v2f r; r.x = a; r.y = b; return r;
}

__global__ __launch_bounds__(64, 2)
void scan_kernel(const float* __restrict__ in, float* __restrict__ out,
                 const float* __restrict__ Wa, const float* __restrict__ ba,
                 const float* __restrict__ Wb, const float* __restrict__ bb,
                 int mode)
{
    __shared__ float xs[2][C64];   // staged input row (double-buffered)
    __shared__ float vs[2][C64];   // recurrent state row (double-buffered)

    const int o   = threadIdx.x;        // lane = channel
    const int g   = blockIdx.x;         // 0..1535 : (b, pos)
    const int b   = g / S;
    const int pos = g - b * S;

    // ---- weights row o into registers, PINNED (non-rematerializable) ----
    v2f wa2[32], wb2[32];
    {
        const float4* A4 = (const float4*)(Wa + o * C64);
        const float4* B4 = (const float4*)(Wb + o * C64);
#pragma unroll
        for (int i = 0; i < 16; ++i) {
            float4 qa = A4[i], qb = B4[i];
            wa2[2*i+0] = mk2(qa.x, qa.y);
            wa2[2*i+1] = mk2(qa.z, qa.w);
            wb2[2*i+0] = mk2(qb.x, qb.y);
            wb2[2*i+1] = mk2(qb.z, qb.w);
        }
#pragma unroll
        for (int i = 0; i < 32; ++i) {
            asm volatile("" : "+v"(wa2[i]));   // pin: value becomes asm-defined,
            asm volatile("" : "+v"(wb2[i]));   // allocator cannot re-load it
        }
    }
    const float bias = ba[o] + bb[o];

    const int inb  = ((b*C64 + o) * S) * S + pos;   // + step*S
    const int outb = ((b*C64 + o) * S + pos) * S;   // + step

    // ---- step 0 init + 3-deep input prefetch ----
    float v0 = in[inb];
    if (mode) v0 = fmaxf(v0, 0.0f);
    vs[1][o] = v0;
    xs[1][o] = in[inb + 1*S];
    float xr  = in[inb + 2*S];
    float xr2 = in[inb + 3*S];
    __builtin_amdgcn_wave_barrier();

    float ob[16];   // 16-step output batch: one full 64B line per lane
    ob[0] = v0;

    // One scan step. H = step index (runtime ok), PAR = H&1 (compile-time),
    // IDX = slot in ob. Tail refills clamp to h=383 (harmless reload).
#define STEP(H, PAR, IDX)                                                     \
    {                                                                         \
        const float4* xq4 = (const float4*)&xs[PAR][0];                       \
        const float4* vq4 = (const float4*)&vs[PAR][0];                       \
        v2f a0 = mk2(bias, 0.0f), a1 = mk2(0.f,0.f);                          \
        v2f a2 = mk2(0.f,0.f),    a3 = mk2(0.f,0.f);                          \
        _Pragma("unroll")                                                     \
        for (int i = 0; i < 16; ++i) {                                        \
            float4 xq = xq4[i];   /* wave-broadcast LDS reads */              \
            float4 vq = vq4[i];                                               \
            a0 = __builtin_elementwise_fma(wa2[2*i+0], mk2(xq.x,xq.y), a0);   \
            a1 = __builtin_elementwise_fma(wa2[2*i+1], mk2(xq.z,xq.w), a1);   \
            a2 = __builtin_elementwise_fma(wb2[2*i+0], mk2(vq.x,vq.y), a2);   \
            a3 = __builtin_elementwise_fma(wb2[2*i+1], mk2(vq.z,vq.w), a3);   \
        }                                                                     \
        v2f sv = (a0 + a1) + (a2 + a3);                                       \
        float vnew = fmaxf(sv.x + sv.y, 0.0f);                                \
        ob[IDX] = vnew;                                                       \
        vs[(PAR) ^ 1][o] = vnew;       /* state for step H+1 */               \
        xs[(PAR) ^ 1][o] = xr;         /* input row for step H+1 */           \
        xr = xr2;                                                             \
        int hn = (H) + 3; hn = (hn > S-1) ? (S-1) : hn;                       \
        xr2 = in[inb + hn * S];                                               \
        __builtin_amdgcn_wave_barrier();                                      \
    }

#define STORE16(BASE)                                                         \
    {                                                                         \
        float4 q0 = {ob[0],  ob[1],  ob[2],  ob[3]};                          \
        float4 q1 = {ob[4],  ob[5],  ob[6],  ob[7]};                          \
        float4 q2 = {ob[8],  ob[9],  ob[10], ob[11]};                         \
        float4 q3 = {ob[12], ob[13], ob[14], ob[15]};                         \
        float4* p = (float4*)(out + outb + (BASE));                           \
        p[0] = q0; p[1] = q1; p[2] = q2; p[3] = q3;                           \
    }

    // ---- peel: steps 1..15, store batch h=0..15 ----
    STEP( 1,1, 1) STEP( 2,0, 2) STEP( 3,1, 3) STEP( 4,0, 4)
    STEP( 5,1, 5) STEP( 6,0, 6) STEP( 7,1, 7) STEP( 8,0, 8)
    STEP( 9,1, 9) STEP(10,0,10) STEP(11,1,11) STEP(12,0,12)
    STEP(13,1,13) STEP(14,0,14) STEP(15,1,15)
    STORE16(0)

    // ---- main: k = 1..23, steps 16k..16k+15, store one line per batch ----
    for (int k = 1; k < 24; ++k) {
        const int h0 = 16 * k;
        STEP(h0+ 0,0, 0) STEP(h0+ 1,1, 1) STEP(h0+ 2,0, 2) STEP(h0+ 3,1, 3)
        STEP(h0+ 4,0, 4) STEP(h0+ 5,1, 5) STEP(h0+ 6,0, 6) STEP(h0+ 7,1, 7)
        STEP(h0+ 8,0, 8) STEP(h0+ 9,1, 9) STEP(h0+10,0,10) STEP(h0+11,1,11)
        STEP(h0+12,0,12) STEP(h0+13,1,13) STEP(h0+14,0,14) STEP(h0+15,1,15)
        STORE16(h0)
    }
#undef STEP
#undef STORE16
}

extern "C" void kernel_launch(void* const* d_in, const int* in_sizes, int n_in,
                              void* d_out, int out_size, void* d_ws, size_t ws_size,
                              hipStream_t stream) {
    const float* x  = (const float*)d_in[0];
    const float* W1 = (const float*)d_in[1];
    const float* b1 = (const float*)d_in[2];
    const float* W2 = (const float*)d_in[3];
    const float* b2 = (const float*)d_in[4];
    const float* W4 = (const float*)d_in[5];
    const float* b4 = (const float*)d_in[6];
    const float* W5 = (const float*)d_in[7];
    const float* b5 = (const float*)d_in[8];
    float* out = (float*)d_out;
    float* hsT = (float*)d_ws;   // B*C*W*H floats of scratch

    dim3 grid(4 * S), block(C64);   // 1536 waves, one per (b, pos)
    // Vertical: reads x[b][c][h][w], writes hsT[b][c][w][h]
    scan_kernel<<<grid, block, 0, stream>>>(x,   hsT, W1, b1, W2, b2, 0);
    // Horizontal: reads hsT[b][c][j][h], writes out[b][c][h][j]
    scan_kernel<<<grid, block, 0, stream>>>(hsT, out, W4, b4, W5, b5, 1);
}